// Round 4
// baseline (334.904 us; speedup 1.0000x reference)
//
#include <hip/hip_runtime.h>

// ---------------------------------------------------------------------------
// ImageTextModule: dual cross-attention between text and image feature sets.
//   t = text @ w_text^T + b_text ; i = image @ w_image^T + b_image  (bf16)
//   P  = exp((t @ i^T) / 32)  materialized ONCE in bf16, BOTH layouts (P, PT);
//        row/col exp-sums fused (wave-pair LDS pre-combine -> 1 atomic per
//        row/col per block).
//   out0 = (scale_TI / lT) * P  @ image ; out1 = (scale_IT / lI) * PT @ text
// attn (v4, THIS round): A-operand direct-from-global, B-only LDS ring.
//   Round-2 analysis: LDS pipe was the wall (reads 128KB + DMA 48KB ≈ 2100cy
//   vs MFMA 1242cy per tile per CU). A-frags are K-contiguous 16B/lane and
//   L2/L3-served -> read them straight into VGPRs (1-tile-ahead ping-pong
//   prefetch, static indexing). LDS now only B: reads 64KB + DMA 16KB ≈
//   940cy < MFMA -> MFMA-bound. Gate vmcnt(2) (2 newest = B-stage of s+2;
//   B of s+1 and a-prefetch drained -> reorder-robust). 48 KB static LDS.
//   B keeps verified ring + chunk16^=(row&7) swizzle (conflicts: 0).
// logits: REVERTED to round-2 verbatim (128x128, 256 thr, 4 blk/CU). The
//   256x128 pipeline port regressed it 68->81 µs: K=1024 is only 16 tiles,
//   and the big serial epilogue at 1 blk/CU had nothing to overlap with.
//   Do not re-port; epilogue-dominated kernels want occupancy, not pipeline.
// proj: 128x64 tiles -> 1024 blocks = 4/CU (prev session: mildly positive).
// Workspace: 96 MB + 32 KB.
// ---------------------------------------------------------------------------

typedef __bf16 bf16x8 __attribute__((ext_vector_type(8)));
typedef float f32x4 __attribute__((ext_vector_type(4)));

#define N_T 4096
#define N_I 4096
#define DIM 1024
#define TSS 136  // epilogue tile stride (bf16): 128 + 8 pad

// attn B ring slot: 128x64 bf16 = 8192 shorts = 16 KB; 3 slots = 48 KB.
#define BT_SLOT 8192

__device__ __forceinline__ unsigned short f2bf(float f) {
    unsigned int u = __float_as_uint(f);
    u += 0x7fffu + ((u >> 16) & 1u);  // RNE
    return (unsigned short)(u >> 16);
}

// 16-byte async global->LDS DMA (no VGPR round-trip).
__device__ __forceinline__ void async_cp16(const unsigned short* g, unsigned short* l) {
    __builtin_amdgcn_global_load_lds(
        (const __attribute__((address_space(1))) unsigned int*)g,
        (__attribute__((address_space(3))) unsigned int*)l, 16, 0, 0);
}

// Stage 128x32 bf16 tile -> unpadded LDS [128][32] with 256 threads.
__device__ __forceinline__ void stage_async(const unsigned short* __restrict__ src,
                                            int ld, int row0, int k0,
                                            unsigned short* lds, int t) {
    int r = t >> 2, c = (t & 3) << 3;
    const unsigned short* g = src + (size_t)(row0 + r) * ld + k0 + c;
    async_cp16(g, lds + r * 32 + c);
    async_cp16(g + (size_t)64 * ld, lds + (64 + r) * 32 + c);
}

// Stage 64x32 bf16 tile -> unpadded LDS [64][32] with 256 threads (1 cp16 ea).
__device__ __forceinline__ void stage_async64(const unsigned short* __restrict__ src,
                                              int ld, int row0, int k0,
                                              unsigned short* lds, int t) {
    int r = t >> 2, c = (t & 3) << 3;
    async_cp16(src + (size_t)(row0 + r) * ld + k0 + c, lds + r * 32 + c);
}

// One BK=32 MFMA step, 4x4 frags (64x64 wave tile) — logits kernel.
__device__ __forceinline__ void mfma_step(const unsigned short* As,
                                          const unsigned short* Bs, f32x4 acc[4][4],
                                          int wrow, int wcol, int lane16, int quad) {
    bf16x8 a[4], b[4];
#pragma unroll
    for (int i = 0; i < 4; ++i) {
        a[i] = *(const bf16x8*)&As[(wrow + i * 16 + lane16) * 32 + quad * 8];
        b[i] = *(const bf16x8*)&Bs[(wcol + i * 16 + lane16) * 32 + quad * 8];
    }
#pragma unroll
    for (int i = 0; i < 4; ++i)
#pragma unroll
        for (int j = 0; j < 4; ++j)
            acc[i][j] = __builtin_amdgcn_mfma_f32_16x16x32_bf16(a[i], b[j], acc[i][j], 0, 0, 0);
}

// One BK=32 MFMA step, 4x2 frags (64x32 wave tile) — proj's 128x64 tiling.
__device__ __forceinline__ void mfma_step42(const unsigned short* As,
                                            const unsigned short* Bs, f32x4 acc[4][2],
                                            int wrow, int wcol, int lane16, int quad) {
    bf16x8 a[4], b[2];
#pragma unroll
    for (int i = 0; i < 4; ++i)
        a[i] = *(const bf16x8*)&As[(wrow + i * 16 + lane16) * 32 + quad * 8];
#pragma unroll
    for (int j = 0; j < 2; ++j)
        b[j] = *(const bf16x8*)&Bs[(wcol + j * 16 + lane16) * 32 + quad * 8];
#pragma unroll
    for (int i = 0; i < 4; ++i)
#pragma unroll
        for (int j = 0; j < 2; ++j)
            acc[i][j] = __builtin_amdgcn_mfma_f32_16x16x32_bf16(a[i], b[j], acc[i][j], 0, 0, 0);
}

// Coalesced 128x128 bf16 tile store from LDS (stride TSS) to global.
__device__ __forceinline__ void tile_store(const unsigned short* sm,
                                           unsigned short* __restrict__ g, int ld,
                                           int row0, int col0, int tid) {
    int r = tid >> 1, h = (tid & 1) << 6;
    const unsigned short* src = sm + r * TSS + h;
    unsigned short* dst = g + (size_t)(row0 + r) * ld + col0 + h;
#pragma unroll
    for (int v = 0; v < 8; ++v)
        *(uint4*)(dst + v * 8) = *(const uint4*)(src + v * 8);
}

// ---- unified pre-pass ------------------------------------------------------
// z=0: image 64x64 tile -> image_bf + imgT      z=1: text -> text_bf + textT
// z=2: weights flat cvt (lin id over 1024 blocks); blocks 0-3 zero lT/lI.
__global__ void __launch_bounds__(256)
cvt_all(const float* __restrict__ im, const float* __restrict__ tx,
        const float* __restrict__ wt, const float* __restrict__ wi,
        unsigned short* __restrict__ imb, unsigned short* __restrict__ txb,
        unsigned short* __restrict__ imgT, unsigned short* __restrict__ textT,
        unsigned short* __restrict__ wtb, unsigned short* __restrict__ wib,
        float* __restrict__ lTI) {
    int t = threadIdx.x;
    if (blockIdx.z == 2) {
        int lin = blockIdx.y * 64 + blockIdx.x;  // 0..1023
        if (lin < 4) {
            *(f32x4*)&lTI[(lin * 256 + t) * 8] = (f32x4){0.f, 0.f, 0.f, 0.f};
            *(f32x4*)&lTI[(lin * 256 + t) * 8 + 4] = (f32x4){0.f, 0.f, 0.f, 0.f};
        }
        size_t i = (size_t)(lin * 256 + t) * 8;
        const float* s;
        unsigned short* d;
        size_t off;
        if (i < 1048576) { s = wt; d = wtb; off = i; }
        else             { s = wi; d = wib; off = i - 1048576; }
        float4 f0 = *(const float4*)(s + off);
        float4 f1 = *(const float4*)(s + off + 4);
        uint4 o;
        o.x = (unsigned int)f2bf(f0.x) | ((unsigned int)f2bf(f0.y) << 16);
        o.y = (unsigned int)f2bf(f0.z) | ((unsigned int)f2bf(f0.w) << 16);
        o.z = (unsigned int)f2bf(f1.x) | ((unsigned int)f2bf(f1.y) << 16);
        o.w = (unsigned int)f2bf(f1.z) | ((unsigned int)f2bf(f1.w) << 16);
        *(uint4*)(d + off) = o;
        return;
    }
    const float* in = blockIdx.z ? tx : im;
    unsigned short* nb = blockIdx.z ? txb : imb;
    unsigned short* tr = blockIdx.z ? textT : imgT;
    __shared__ float tile[64][65];
    int row0 = blockIdx.x * 64, col0 = blockIdx.y * 64;
    int r = t >> 2, c = (t & 3) << 4;  // 64 rows x 4 col-chunks of 16
    {
        const float* p = in + (size_t)(row0 + r) * DIM + col0 + c;
        float4 f0 = *(const float4*)(p);
        float4 f1 = *(const float4*)(p + 4);
        float4 f2 = *(const float4*)(p + 8);
        float4 f3 = *(const float4*)(p + 12);
        *(float4*)&tile[r][c] = f0;
        *(float4*)&tile[r][c + 4] = f1;
        *(float4*)&tile[r][c + 8] = f2;
        *(float4*)&tile[r][c + 12] = f3;
        uint4 o0, o1;
        o0.x = (unsigned int)f2bf(f0.x) | ((unsigned int)f2bf(f0.y) << 16);
        o0.y = (unsigned int)f2bf(f0.z) | ((unsigned int)f2bf(f0.w) << 16);
        o0.z = (unsigned int)f2bf(f1.x) | ((unsigned int)f2bf(f1.y) << 16);
        o0.w = (unsigned int)f2bf(f1.z) | ((unsigned int)f2bf(f1.w) << 16);
        o1.x = (unsigned int)f2bf(f2.x) | ((unsigned int)f2bf(f2.y) << 16);
        o1.y = (unsigned int)f2bf(f2.z) | ((unsigned int)f2bf(f2.w) << 16);
        o1.z = (unsigned int)f2bf(f3.x) | ((unsigned int)f2bf(f3.y) << 16);
        o1.w = (unsigned int)f2bf(f3.z) | ((unsigned int)f2bf(f3.w) << 16);
        unsigned short* q = nb + (size_t)(row0 + r) * DIM + col0 + c;
        *(uint4*)q = o0;
        *(uint4*)(q + 8) = o1;
    }
    __syncthreads();
    {
        unsigned short v[16];
#pragma unroll
        for (int u = 0; u < 16; ++u) v[u] = f2bf(tile[c + u][r]);
        unsigned short* q = tr + (size_t)(col0 + r) * N_T + row0 + c;
        *(uint4*)q = *(uint4*)&v[0];
        *(uint4*)(q + 8) = *(uint4*)&v[8];
    }
}

// ---- fused projections: 128x64 tiles, 1024 blocks = 4/CU, 32 waves/CU ------
// C_bf16[4096][1024] = A_bf16 @ W_bf16^T + bias.  z: text / image.
__global__ void __launch_bounds__(256, 4)
gemm_proj2(const unsigned short* __restrict__ Atx, const unsigned short* __restrict__ Wtx,
           const float* __restrict__ btx, unsigned short* __restrict__ Ctx,
           const unsigned short* __restrict__ Aim, const unsigned short* __restrict__ Wim,
           const float* __restrict__ bim, unsigned short* __restrict__ Cim) {
    __shared__ unsigned short As[2][128 * 32];  // 16 KB
    __shared__ unsigned short Bs[2][64 * 32];   // 8 KB
    int z = blockIdx.z;
    const unsigned short* A = z ? Aim : Atx;
    const unsigned short* W = z ? Wim : Wtx;
    const float* bias = z ? bim : btx;
    unsigned short* C = z ? Cim : Ctx;
    int tid = threadIdx.x;
    int m0 = blockIdx.x * 128, n0 = blockIdx.y * 64;
    int lane = tid & 63, wave = tid >> 6;
    int lane16 = lane & 15, quad = lane >> 4;
    int wrow = (wave >> 1) * 64, wcol = (wave & 1) * 32;
    f32x4 acc[4][2];
    {
        f32x4 zz = {0.f, 0.f, 0.f, 0.f};
        for (int i = 0; i < 4; ++i)
            for (int j = 0; j < 2; ++j) acc[i][j] = zz;
    }
    for (int k0 = 0; k0 < DIM; k0 += 64) {
        stage_async(A, DIM, m0, k0, As[0], tid);
        stage_async64(W, DIM, n0, k0, Bs[0], tid);
        stage_async(A, DIM, m0, k0 + 32, As[1], tid);
        stage_async64(W, DIM, n0, k0 + 32, Bs[1], tid);
        __syncthreads();
        mfma_step42(As[0], Bs[0], acc, wrow, wcol, lane16, quad);
        mfma_step42(As[1], Bs[1], acc, wrow, wcol, lane16, quad);
        __syncthreads();
    }
#pragma unroll
    for (int j = 0; j < 2; ++j) {
        int col = n0 + wcol + j * 16 + lane16;
        float bv = bias[col];
#pragma unroll
        for (int i = 0; i < 4; ++i) {
            int rowb = m0 + wrow + i * 16 + quad * 4;
#pragma unroll
            for (int r = 0; r < 4; ++r)
                C[(size_t)(rowb + r) * DIM + col] = f2bf(acc[i][j][r] + bv);
        }
    }
}

// ---- logits+exp: P/PT bf16 (both layouts) + fused row/col exp-sums ---------
// Round-2 verified version (128x128, 256 thr, 4 blk/CU). Wave-pair LDS
// pre-combine -> one atomic per row/col per block.
__global__ void __launch_bounds__(256, 4)
gemm_logits_exp(const unsigned short* __restrict__ Tb,
                const unsigned short* __restrict__ Ib,
                unsigned short* __restrict__ P, unsigned short* __restrict__ PT,
                float* __restrict__ lT, float* __restrict__ lI) {
    __shared__ unsigned short smem[128 * TSS];  // 34.8 KB: K-bufs + epilogue
    unsigned short* As0 = smem;
    unsigned short* Bs0 = smem + 4096;
    unsigned short* As1 = smem + 8192;
    unsigned short* Bs1 = smem + 12288;
    float* lred = (float*)(smem + 16384);  // 128 floats (free tail of smem)
    float* cred = lred + 128;              // 128 floats
    int tid = threadIdx.x;
    int m0 = blockIdx.x * 128, n0 = blockIdx.y * 128;
    int lane = tid & 63, wave = tid >> 6;
    int lane16 = lane & 15, quad = lane >> 4;
    int wrow = (wave >> 1) * 64, wcol = (wave & 1) * 64;
    f32x4 acc[4][4];
    {
        f32x4 z = {0.f, 0.f, 0.f, 0.f};
        for (int i = 0; i < 4; ++i)
            for (int j = 0; j < 4; ++j) acc[i][j] = z;
    }
    for (int k0 = 0; k0 < DIM; k0 += 64) {
        stage_async(Tb, DIM, m0, k0, As0, tid);
        stage_async(Ib, DIM, n0, k0, Bs0, tid);
        stage_async(Tb, DIM, m0, k0 + 32, As1, tid);
        stage_async(Ib, DIM, n0, k0 + 32, Bs1, tid);
        __syncthreads();
        mfma_step(As0, Bs0, acc, wrow, wcol, lane16, quad);
        mfma_step(As1, Bs1, acc, wrow, wcol, lane16, quad);
        __syncthreads();
    }
    // p = exp(logit/32) in place (fp32)
#pragma unroll
    for (int i = 0; i < 4; ++i)
#pragma unroll
        for (int j = 0; j < 4; ++j)
#pragma unroll
            for (int r = 0; r < 4; ++r)
                acc[i][j][r] = __expf(acc[i][j][r] * 0.03125f);
    // wave partials: rows (this wave's 64 cols) and cols (this wave's 64 rows)
    float rs[4][4];  // row partial, valid at lane16==0
#pragma unroll
    for (int i = 0; i < 4; ++i)
#pragma unroll
        for (int r = 0; r < 4; ++r) {
            float s = acc[i][0][r] + acc[i][1][r] + acc[i][2][r] + acc[i][3][r];
            s += __shfl_xor(s, 1); s += __shfl_xor(s, 2);
            s += __shfl_xor(s, 4); s += __shfl_xor(s, 8);
            rs[i][r] = s;
        }
    float cs[4];  // col partial, valid at quad==0
#pragma unroll
    for (int j = 0; j < 4; ++j) {
        float s = 0.f;
#pragma unroll
        for (int i = 0; i < 4; ++i)
#pragma unroll
            for (int r = 0; r < 4; ++r) s += acc[i][j][r];
        s += __shfl_xor(s, 16); s += __shfl_xor(s, 32);
        cs[j] = s;
    }
    // donors: waves 1,3 stash row partials; waves 2,3 stash col partials
    if (wave & 1) {
        if (lane16 == 0)
#pragma unroll
            for (int i = 0; i < 4; ++i)
#pragma unroll
                for (int r = 0; r < 4; ++r)
                    lred[wrow + i * 16 + quad * 4 + r] = rs[i][r];
    }
    if (wave >> 1) {
        if (quad == 0)
#pragma unroll
            for (int j = 0; j < 4; ++j)
                cred[wcol + j * 16 + lane16] = cs[j];
    }
    __syncthreads();
    // combiners: waves 0,2 finish rows; waves 0,1 finish cols
    if (!(wave & 1) && lane16 == 0) {
#pragma unroll
        for (int i = 0; i < 4; ++i)
#pragma unroll
            for (int r = 0; r < 4; ++r) {
                int row = wrow + i * 16 + quad * 4 + r;
                atomicAdd(&lT[m0 + row], rs[i][r] + lred[row]);
            }
    }
    if (!(wave >> 1) && quad == 0) {
#pragma unroll
        for (int j = 0; j < 4; ++j) {
            int col = wcol + j * 16 + lane16;
            atomicAdd(&lI[n0 + col], cs[j] + cred[col]);
        }
    }
    // pass 1: normal-layout tile -> P (coalesced b128 stores)
    __syncthreads();
#pragma unroll
    for (int i = 0; i < 4; ++i)
#pragma unroll
        for (int j = 0; j < 4; ++j)
#pragma unroll
            for (int r = 0; r < 4; ++r)
                smem[(wrow + i * 16 + quad * 4 + r) * TSS + wcol + j * 16 + lane16] =
                    f2bf(acc[i][j][r]);
    __syncthreads();
    tile_store(smem, P, N_I, m0, n0, tid);
    // pass 2: transposed tile -> PT (b64 LDS writes, coalesced b128 stores)
    __syncthreads();
#pragma unroll
    for (int i = 0; i < 4; ++i)
#pragma unroll
        for (int j = 0; j < 4; ++j) {
            unsigned int lo = (unsigned int)f2bf(acc[i][j][0]) |
                              ((unsigned int)f2bf(acc[i][j][1]) << 16);
            unsigned int hi = (unsigned int)f2bf(acc[i][j][2]) |
                              ((unsigned int)f2bf(acc[i][j][3]) << 16);
            uint2 v; v.x = lo; v.y = hi;
            *(uint2*)&smem[(wcol + j * 16 + lane16) * TSS + wrow + i * 16 + quad * 4] = v;
        }
    __syncthreads();
    tile_store(smem, PT, N_T, n0, m0, tid);
}

// ---- attn v4: A-from-global, B-only LDS ring, fine phases ------------------
// B slot [128][64] bf16, chunk16 ^= (row&7) swizzle on BOTH gload source
// (inverse) and ds_read addr (verified: conflicts 0).

// Stage B half h (64 rows, 512 chunks, 1 per thread of 512).
__device__ __forceinline__ void at_stageB_half(const unsigned short* __restrict__ g,
                                               int row0, int k0, unsigned short* lds,
                                               int t, int h) {
    int c = t + h * 512;
    int r = c >> 3;
    int kq = (c & 7) ^ (r & 7);
    async_cp16(g + (size_t)(row0 + r) * 4096 + k0 + (kq << 3), lds + c * 8);
}
__device__ __forceinline__ void at_stageB(const unsigned short* __restrict__ g,
                                          int row0, int k0, unsigned short* lds, int t) {
    at_stageB_half(g, row0, k0, lds, t, 0);
    at_stageB_half(g, row0, k0, lds, t, 1);
}

// Load this wave's 8 a-fragments (4 row-frags x 2 K-slices) for K-tile k0
// straight from global. Per lane: 16B K-contiguous; 4 lanes/row cover one
// full 64B line -> fully-utilized L2 sectors.
__device__ __forceinline__ void load_afrags(const unsigned short* Arow, int k0,
                                            bf16x8 a[8]) {
#pragma unroll
    for (int i = 0; i < 4; ++i)
#pragma unroll
        for (int ks = 0; ks < 2; ++ks)
            a[i * 2 + ks] = *(const bf16x8*)(Arow + (size_t)i * 16 * 4096 + k0 + ks * 32);
}

// One sub-phase: 4 swizzled B ds_read_b128 + optional B-stage-half of tile
// s+2 + 16 MFMA under setprio(1) using prefetched a-regs.
template <int DO_STAGE>
__device__ __forceinline__ void at4_sub(const unsigned short* Bs, const bf16x8 a[8],
                                        const unsigned short* __restrict__ Bt,
                                        int n0, int kst, unsigned short* nsl,
                                        int t, f32x4 acc[4][4],
                                        int wcol, int lane16, int quad, int ks) {
    bf16x8 b[4];
    int sw = (((ks << 2) | quad) ^ (lane16 & 7)) << 3;  // row&7 == lane16&7
#pragma unroll
    for (int j = 0; j < 4; ++j)
        b[j] = *(const bf16x8*)&Bs[(wcol + j * 16 + lane16) * 64 + sw];
    if (DO_STAGE)
        at_stageB_half(Bt, n0, kst, nsl, t, ks);
    __builtin_amdgcn_s_setprio(1);
#pragma unroll
    for (int i = 0; i < 4; ++i)
#pragma unroll
        for (int j = 0; j < 4; ++j)
            acc[i][j] = __builtin_amdgcn_mfma_f32_16x16x32_bf16(a[i * 2 + ks], b[j],
                                                               acc[i][j], 0, 0, 0);
    __builtin_amdgcn_s_setprio(0);
}

// One staged tile: prefetch a_{s+1} -> aN (pinned first), stage B_{s+2},
// compute with aC. End gate vmcnt(2): the 2 newest outstanding VMEM ops are
// B_{s+2}'s two cp16s; B_{s+1} (older) and a_{s+1} are drained -> reads of
// the next slot are safe after the barrier regardless of issue reordering.
// lgkmcnt(0): this slot's ds_reads retired before tile s+1 re-stages it.
__device__ __forceinline__ void at4_tile(const unsigned short* Bs, unsigned short* nsl,
                                         const unsigned short* Arow,
                                         const unsigned short* __restrict__ Bt,
                                         int n0, int ka, int kb,
                                         const bf16x8 aC[8], bf16x8 aN[8],
                                         int t, f32x4 acc[4][4],
                                         int wcol, int lane16, int quad) {
    load_afrags(Arow, ka, aN);
    __builtin_amdgcn_sched_barrier(0);  // pin a-loads before b-reads/stages
    at4_sub<1>(Bs, aC, Bt, n0, kb, nsl, t, acc, wcol, lane16, quad, 0);
    asm volatile("" ::: "memory");
    __builtin_amdgcn_s_barrier();
    asm volatile("" ::: "memory");
    at4_sub<1>(Bs, aC, Bt, n0, kb, nsl, t, acc, wcol, lane16, quad, 1);
    asm volatile("s_waitcnt vmcnt(2) lgkmcnt(0)" ::: "memory");
    __builtin_amdgcn_s_barrier();
}

// grid (16, 8, 2), 512 thr / 8 waves (4Mx2N, wave 64x64), 48 KB static LDS.
__global__ void __launch_bounds__(512)
gemm_attn4(const unsigned short* __restrict__ P, const unsigned short* __restrict__ imgT,
           const float* __restrict__ lT, const float* __restrict__ sTI,
           float* __restrict__ out0,
           const unsigned short* __restrict__ PT, const unsigned short* __restrict__ textT,
           const float* __restrict__ lI, const float* __restrict__ sIT,
           float* __restrict__ out1) {
    __shared__ unsigned short Bsm[3 * BT_SLOT];  // 48 KB
    int which = blockIdx.z;
    const unsigned short* A = which ? PT : P;
    const unsigned short* Bt = which ? textT : imgT;
    const float* l = which ? lI : lT;
    const float* sp = which ? sIT : sTI;
    float* out = which ? out1 : out0;

    int tid = threadIdx.x;
    int m0 = blockIdx.x * 256, n0 = blockIdx.y * 128;
    int lane = tid & 63, wave = tid >> 6;
    int lane16 = lane & 15, quad = lane >> 4;
    int wrow = (wave >> 1) * 64, wcol = (wave & 1) * 64;  // 4M x 2N waves
    const unsigned short* Arow = A + (size_t)(m0 + wrow + lane16) * 4096 + quad * 8;
    f32x4 acc[4][4];
    {
        f32x4 z = {0.f, 0.f, 0.f, 0.f};
        for (int i = 0; i < 4; ++i)
            for (int j = 0; j < 4; ++j) acc[i][j] = z;
    }
    bf16x8 aA[8], aB[8];

    // prologue: B slots 0,1 <- tiles 0,1 (4 cp); a0 -> aA (8 loads).
    // vmcnt(10): B0's 2 cp (oldest) landed; a0 gated by compiler reg-deps.
    at_stageB(Bt, n0, 0, Bsm, tid);
    at_stageB(Bt, n0, 64, Bsm + BT_SLOT, tid);
    load_afrags(Arow, 0, aA);
    asm volatile("s_waitcnt vmcnt(10)" ::: "memory");
    __builtin_amdgcn_s_barrier();

    int cur = 0;
    // tiles 0..61 (staged), unrolled x2 for static a ping-pong (rule 20)
    for (int s2 = 0; s2 < 31; ++s2) {
        int s = s2 * 2;
        {
            int ns = cur + 2; if (ns >= 3) ns -= 3;
            at4_tile(Bsm + cur * BT_SLOT, Bsm + ns * BT_SLOT, Arow, Bt, n0,
                     (s + 1) * 64, (s + 2) * 64, aA, aB, tid, acc, wcol, lane16, quad);
            cur += 1; if (cur >= 3) cur -= 3;
        }
        {
            int ns = cur + 2; if (ns >= 3) ns -= 3;
            at4_tile(Bsm + cur * BT_SLOT, Bsm + ns * BT_SLOT, Arow, Bt, n0,
                     (s + 2) * 64, (s + 3) * 64, aB, aA, tid, acc, wcol, lane16, quad);
            cur += 1; if (cur >= 3) cur -= 3;
        }
    }
    // tile 62: use aA, prefetch a63 -> aB, no B-stage; drain gate vmcnt(0).
    {
        const unsigned short* Bs = Bsm + cur * BT_SLOT;
        load_afrags(Arow, 63 * 64, aB);
        __builtin_amdgcn_sched_barrier(0);
        at4_sub<0>(Bs, aA, nullptr, 0, 0, nullptr, tid, acc, wcol, lane16, quad, 0);
        asm volatile("" ::: "memory");
        __builtin_amdgcn_s_barrier();
        asm volatile("" ::: "memory");
        at4_sub<0>(Bs, aA, nullptr, 0, 0, nullptr, tid, acc, wcol, lane16, quad, 1);
        asm volatile("s_waitcnt vmcnt(0) lgkmcnt(0)" ::: "memory");
        __builtin_amdgcn_s_barrier();
        cur += 1; if (cur >= 3) cur -= 3;
    }
    // tile 63: compute only (no stage, no barriers after).
    {
        const unsigned short* Bs = Bsm + cur * BT_SLOT;
        at4_sub<0>(Bs, aB, nullptr, 0, 0, nullptr, tid, acc, wcol, lane16, quad, 0);
        at4_sub<0>(Bs, aB, nullptr, 0, 0, nullptr, tid, acc, wcol, lane16, quad, 1);
    }

    float sc = sp[0];
#pragma unroll
    for (int i = 0; i < 4; ++i) {
        int rowb = m0 + wrow + i * 16 + quad * 4;
        float fac[4];
#pragma unroll
        for (int r = 0; r < 4; ++r) fac[r] = sc / l[rowb + r];
#pragma unroll
        for (int j = 0; j < 4; ++j) {
            int col = n0 + wcol + j * 16 + lane16;
#pragma unroll
            for (int r = 0; r < 4; ++r)
                out[(size_t)(rowb + r) * DIM + col] = acc[i][j][r] * fac[r];
        }
    }
}

extern "C" void kernel_launch(void* const* d_in, const int* in_sizes, int n_in,
                              void* d_out, int out_size, void* d_ws, size_t ws_size,
                              hipStream_t stream) {
    const float* text = (const float*)d_in[0];
    const float* image = (const float*)d_in[1];
    const float* w_text = (const float*)d_in[2];
    const float* b_text = (const float*)d_in[3];
    const float* w_image = (const float*)d_in[4];
    const float* b_image = (const float*)d_in[5];
    const float* scale_TI = (const float*)d_in[6];
    const float* scale_IT = (const float*)d_in[7];
    float* out0 = (float*)d_out;
    float* out1 = out0 + (size_t)N_T * DIM;

    // Workspace layout (96 MB + 32 KB). cvt buffers [0,20MB) die after proj2;
    // gemm_logits_exp then writes P over [0,32MB) — lifetimes disjoint.
    char* ws = (char*)d_ws;
    unsigned short* text_bf = (unsigned short*)(ws);                 // 8 MB  (dies after proj)
    unsigned short* image_bf = (unsigned short*)(ws + (8ull << 20)); // 8 MB  (dies after proj)
    unsigned short* wt_bf = (unsigned short*)(ws + (16ull << 20));   // 2 MB  (dies after proj)
    unsigned short* wi_bf = (unsigned short*)(ws + (18ull << 20));   // 2 MB  (dies after proj)
    unsigned short* P = (unsigned short*)(ws);                       // 32 MB (logits -> attn)
    unsigned short* imgT = (unsigned short*)(ws + (32ull << 20));    // 8 MB
    unsigned short* textT = (unsigned short*)(ws + (40ull << 20));   // 8 MB
    unsigned short* t_bf = (unsigned short*)(ws + (48ull << 20));    // 8 MB
    unsigned short* i_bf = (unsigned short*)(ws + (56ull << 20));    // 8 MB
    unsigned short* PT = (unsigned short*)(ws + (64ull << 20));      // 32 MB
    float* lT = (float*)(ws + (96ull << 20));                        // 16 KB
    float* lI = (float*)(ws + (96ull << 20) + 16384);                // 16 KB

    // z=0/1: feature 64x64 cvt+transpose tiles; z=2: weights cvt + lT/lI zero.
    cvt_all<<<dim3(N_T / 64, DIM / 64, 3), 256, 0, stream>>>(
        image, text, w_text, w_image, image_bf, text_bf, imgT, textT,
        wt_bf, wi_bf, lT);

    gemm_proj2<<<dim3(N_T / 128, DIM / 64, 2), 256, 0, stream>>>(
        text_bf, wt_bf, b_text, t_bf, image_bf, wi_bf, b_image, i_bf);

    gemm_logits_exp<<<dim3(N_T / 128, N_I / 128), 256, 0, stream>>>(t_bf, i_bf, P, PT, lT, lI);

    gemm_attn4<<<dim3(N_T / 256, DIM / 128, 2), 512, 0, stream>>>(
        P, imgT, lT, scale_TI, out0, PT, textT, lI, scale_IT, out1);
}

// Round 5
// 251.439 us; speedup vs baseline: 1.3320x; 1.3320x over previous
//
#include <hip/hip_runtime.h>

// ---------------------------------------------------------------------------
// ImageTextModule: dual cross-attention between text and image feature sets.
//   t = text @ w_text^T + b_text ; i = image @ w_image^T + b_image  (bf16)
//   P  = exp((t @ i^T) / 32)  materialized ONCE in bf16, BOTH layouts (P, PT);
//        row/col exp-sums fused (wave-pair LDS pre-combine -> 1 atomic per
//        row/col per block).
//   out0 = (scale_TI / lT) * P  @ image ; out1 = (scale_IT / lI) * PT @ text
// attn (v3 + XCD swizzle, THIS round): fine-phase counted-vmcnt pipeline
//   (verified r2: 68.2 µs, conflicts 0) + XCD-aware block remap.
//   EVIDENCE (r0/r2/r4): all attn variants saturate ~11.5 TB/s aggregate
//   cache-fabric reads (baseline 1GB/86.6µs, attn3 768MB/68.2µs, v4-regression
//   1.28GB/158µs). attn3 is FABRIC-bound, not LDS-bound. v4 (A-from-global,
//   158 µs) added 66% traffic -> reverted; do not retry register-A.
//   Remap: xcd = z*4 + n/2, within-XCD m-major, n-pair interleaved ->
//   B panels L2-resident per XCD, A panels read pair-concurrently:
//   L3 reads 768 -> ~272 MB. Bijective; correctness mapping-independent.
// logits (r2-verified 128x128/256thr/4blk-CU + XCD swizzle): reads 512MB at
//   ~9 TB/s -> also fabric-bound. Remap xcd = n/4: B band (1MB) pinned in
//   XCD L2, A once per XCD -> ~72 MB. DO NOT re-port the 1-blk/CU pipeline
//   here (r3: 81 µs — epilogue needs occupancy overlap).
// proj: 128x64 tiles -> 1024 blocks = 4/CU (prev session: mildly positive).
// Workspace: 96 MB + 32 KB.
// ---------------------------------------------------------------------------

typedef __bf16 bf16x8 __attribute__((ext_vector_type(8)));
typedef float f32x4 __attribute__((ext_vector_type(4)));

#define N_T 4096
#define N_I 4096
#define DIM 1024
#define TSS 136  // epilogue tile stride (bf16): 128 + 8 pad

// attn ring slot: A 256x64 bf16 (16384 sh) + B 128x64 bf16 (8192 sh) = 48 KB
#define AT_SLOT 24576
#define AT_LDS_BYTES (3 * AT_SLOT * 2)  // 147456 B = 144 KB

__device__ __forceinline__ unsigned short f2bf(float f) {
    unsigned int u = __float_as_uint(f);
    u += 0x7fffu + ((u >> 16) & 1u);  // RNE
    return (unsigned short)(u >> 16);
}

// 16-byte async global->LDS DMA (no VGPR round-trip).
__device__ __forceinline__ void async_cp16(const unsigned short* g, unsigned short* l) {
    __builtin_amdgcn_global_load_lds(
        (const __attribute__((address_space(1))) unsigned int*)g,
        (__attribute__((address_space(3))) unsigned int*)l, 16, 0, 0);
}

// Stage 128x32 bf16 tile -> unpadded LDS [128][32] with 256 threads.
__device__ __forceinline__ void stage_async(const unsigned short* __restrict__ src,
                                            int ld, int row0, int k0,
                                            unsigned short* lds, int t) {
    int r = t >> 2, c = (t & 3) << 3;
    const unsigned short* g = src + (size_t)(row0 + r) * ld + k0 + c;
    async_cp16(g, lds + r * 32 + c);
    async_cp16(g + (size_t)64 * ld, lds + (64 + r) * 32 + c);
}

// Stage 64x32 bf16 tile -> unpadded LDS [64][32] with 256 threads (1 cp16 ea).
__device__ __forceinline__ void stage_async64(const unsigned short* __restrict__ src,
                                              int ld, int row0, int k0,
                                              unsigned short* lds, int t) {
    int r = t >> 2, c = (t & 3) << 3;
    async_cp16(src + (size_t)(row0 + r) * ld + k0 + c, lds + r * 32 + c);
}

// One BK=32 MFMA step, 4x4 frags (64x64 wave tile) — logits kernel.
__device__ __forceinline__ void mfma_step(const unsigned short* As,
                                          const unsigned short* Bs, f32x4 acc[4][4],
                                          int wrow, int wcol, int lane16, int quad) {
    bf16x8 a[4], b[4];
#pragma unroll
    for (int i = 0; i < 4; ++i) {
        a[i] = *(const bf16x8*)&As[(wrow + i * 16 + lane16) * 32 + quad * 8];
        b[i] = *(const bf16x8*)&Bs[(wcol + i * 16 + lane16) * 32 + quad * 8];
    }
#pragma unroll
    for (int i = 0; i < 4; ++i)
#pragma unroll
        for (int j = 0; j < 4; ++j)
            acc[i][j] = __builtin_amdgcn_mfma_f32_16x16x32_bf16(a[i], b[j], acc[i][j], 0, 0, 0);
}

// One BK=32 MFMA step, 4x2 frags (64x32 wave tile) — proj's 128x64 tiling.
__device__ __forceinline__ void mfma_step42(const unsigned short* As,
                                            const unsigned short* Bs, f32x4 acc[4][2],
                                            int wrow, int wcol, int lane16, int quad) {
    bf16x8 a[4], b[2];
#pragma unroll
    for (int i = 0; i < 4; ++i)
        a[i] = *(const bf16x8*)&As[(wrow + i * 16 + lane16) * 32 + quad * 8];
#pragma unroll
    for (int j = 0; j < 2; ++j)
        b[j] = *(const bf16x8*)&Bs[(wcol + j * 16 + lane16) * 32 + quad * 8];
#pragma unroll
    for (int i = 0; i < 4; ++i)
#pragma unroll
        for (int j = 0; j < 2; ++j)
            acc[i][j] = __builtin_amdgcn_mfma_f32_16x16x32_bf16(a[i], b[j], acc[i][j], 0, 0, 0);
}

// Coalesced 128x128 bf16 tile store from LDS (stride TSS) to global.
__device__ __forceinline__ void tile_store(const unsigned short* sm,
                                           unsigned short* __restrict__ g, int ld,
                                           int row0, int col0, int tid) {
    int r = tid >> 1, h = (tid & 1) << 6;
    const unsigned short* src = sm + r * TSS + h;
    unsigned short* dst = g + (size_t)(row0 + r) * ld + col0 + h;
#pragma unroll
    for (int v = 0; v < 8; ++v)
        *(uint4*)(dst + v * 8) = *(const uint4*)(src + v * 8);
}

// ---- fine-phase pipeline stagers (attn) ------------------------------------
// LDS ring slot: A [256][64] bf16 (chunk16-swizzled), B [128][64].
// Swizzle: 16B-chunk index within a row ^= (row & 7) -> conflict-free
// (measured 0). Applied BOTH at the gload source (inverse) and ds_read addr.

// Stage A half h (128 rows, 1024 chunks, 2 per thread; LDS dest linear).
template <int LD>
__device__ __forceinline__ void at_stageA_half(const unsigned short* __restrict__ g,
                                               int row0, int k0, unsigned short* lds,
                                               int t, int h) {
#pragma unroll
    for (int u = 0; u < 2; ++u) {
        int c = t + (h * 2 + u) * 512;
        int r = c >> 3;
        int kq = (c & 7) ^ (r & 7);  // inverse-swizzled global chunk
        async_cp16(g + (size_t)(row0 + r) * LD + k0 + (kq << 3), lds + c * 8);
    }
}

// Stage B half h (64 rows, 512 chunks, 1 per thread).
template <int LD>
__device__ __forceinline__ void at_stageB_half(const unsigned short* __restrict__ g,
                                               int row0, int k0, unsigned short* lds,
                                               int t, int h) {
    int c = t + h * 512;
    int r = c >> 3;
    int kq = (c & 7) ^ (r & 7);
    async_cp16(g + (size_t)(row0 + r) * LD + k0 + (kq << 3), lds + c * 8);
}

// Full-tile stagers (prologue only).
template <int LD>
__device__ __forceinline__ void at_stageA(const unsigned short* __restrict__ g,
                                          int row0, int k0, unsigned short* lds, int t) {
    at_stageA_half<LD>(g, row0, k0, lds, t, 0);
    at_stageA_half<LD>(g, row0, k0, lds, t, 1);
}
template <int LD>
__device__ __forceinline__ void at_stageB(const unsigned short* __restrict__ g,
                                          int row0, int k0, unsigned short* lds, int t) {
    at_stageB_half<LD>(g, row0, k0, lds, t, 0);
    at_stageB_half<LD>(g, row0, k0, lds, t, 1);
}

// One sub-phase: 8 swizzled ds_read_b128 (K-slice ks of slot cp) + stage-half
// ks of tile s+2 into nsl + 16 MFMA under setprio(1). 16-MFMA grain = the
// m196/m201-proven interleave unit; compiler inserts fine lgkmcnt for the
// read->MFMA deps (no manual waits inside -> rule-18 safe).
template <int LD, int DO_STAGE>
__device__ __forceinline__ void at_sub(const unsigned short* cp,
                                       const unsigned short* __restrict__ A,
                                       const unsigned short* __restrict__ Bt,
                                       int m0, int n0, int kst, unsigned short* nsl,
                                       int t, f32x4 acc[4][4],
                                       int wrow, int wcol, int lane16, int quad, int ks) {
    const unsigned short* As = cp;
    const unsigned short* Bs = cp + 16384;
    bf16x8 a[4], b[4];
    int sw = (((ks << 2) | quad) ^ (lane16 & 7)) << 3;  // row&7 == lane16&7
#pragma unroll
    for (int i = 0; i < 4; ++i)
        a[i] = *(const bf16x8*)&As[(wrow + i * 16 + lane16) * 64 + sw];
#pragma unroll
    for (int j = 0; j < 4; ++j)
        b[j] = *(const bf16x8*)&Bs[(wcol + j * 16 + lane16) * 64 + sw];
    if (DO_STAGE) {
        at_stageA_half<LD>(A, m0, kst, nsl, t, ks);
        at_stageB_half<LD>(Bt, n0, kst, nsl + 16384, t, ks);
    }
    __builtin_amdgcn_s_setprio(1);
#pragma unroll
    for (int i = 0; i < 4; ++i)
#pragma unroll
        for (int j = 0; j < 4; ++j)
            acc[i][j] = __builtin_amdgcn_mfma_f32_16x16x32_bf16(a[i], b[j], acc[i][j], 0, 0, 0);
    __builtin_amdgcn_s_setprio(0);
}

// ---- unified pre-pass ------------------------------------------------------
// z=0: image 64x64 tile -> image_bf + imgT      z=1: text -> text_bf + textT
// z=2: weights flat cvt (lin id over 1024 blocks); blocks 0-3 zero lT/lI.
__global__ void __launch_bounds__(256)
cvt_all(const float* __restrict__ im, const float* __restrict__ tx,
        const float* __restrict__ wt, const float* __restrict__ wi,
        unsigned short* __restrict__ imb, unsigned short* __restrict__ txb,
        unsigned short* __restrict__ imgT, unsigned short* __restrict__ textT,
        unsigned short* __restrict__ wtb, unsigned short* __restrict__ wib,
        float* __restrict__ lTI) {
    int t = threadIdx.x;
    if (blockIdx.z == 2) {
        int lin = blockIdx.y * 64 + blockIdx.x;  // 0..1023
        if (lin < 4) {
            *(f32x4*)&lTI[(lin * 256 + t) * 8] = (f32x4){0.f, 0.f, 0.f, 0.f};
            *(f32x4*)&lTI[(lin * 256 + t) * 8 + 4] = (f32x4){0.f, 0.f, 0.f, 0.f};
        }
        size_t i = (size_t)(lin * 256 + t) * 8;
        const float* s;
        unsigned short* d;
        size_t off;
        if (i < 1048576) { s = wt; d = wtb; off = i; }
        else             { s = wi; d = wib; off = i - 1048576; }
        float4 f0 = *(const float4*)(s + off);
        float4 f1 = *(const float4*)(s + off + 4);
        uint4 o;
        o.x = (unsigned int)f2bf(f0.x) | ((unsigned int)f2bf(f0.y) << 16);
        o.y = (unsigned int)f2bf(f0.z) | ((unsigned int)f2bf(f0.w) << 16);
        o.z = (unsigned int)f2bf(f1.x) | ((unsigned int)f2bf(f1.y) << 16);
        o.w = (unsigned int)f2bf(f1.z) | ((unsigned int)f2bf(f1.w) << 16);
        *(uint4*)(d + off) = o;
        return;
    }
    const float* in = blockIdx.z ? tx : im;
    unsigned short* nb = blockIdx.z ? txb : imb;
    unsigned short* tr = blockIdx.z ? textT : imgT;
    __shared__ float tile[64][65];
    int row0 = blockIdx.x * 64, col0 = blockIdx.y * 64;
    int r = t >> 2, c = (t & 3) << 4;  // 64 rows x 4 col-chunks of 16
    {
        const float* p = in + (size_t)(row0 + r) * DIM + col0 + c;
        float4 f0 = *(const float4*)(p);
        float4 f1 = *(const float4*)(p + 4);
        float4 f2 = *(const float4*)(p + 8);
        float4 f3 = *(const float4*)(p + 12);
        *(float4*)&tile[r][c] = f0;
        *(float4*)&tile[r][c + 4] = f1;
        *(float4*)&tile[r][c + 8] = f2;
        *(float4*)&tile[r][c + 12] = f3;
        uint4 o0, o1;
        o0.x = (unsigned int)f2bf(f0.x) | ((unsigned int)f2bf(f0.y) << 16);
        o0.y = (unsigned int)f2bf(f0.z) | ((unsigned int)f2bf(f0.w) << 16);
        o0.z = (unsigned int)f2bf(f1.x) | ((unsigned int)f2bf(f1.y) << 16);
        o0.w = (unsigned int)f2bf(f1.z) | ((unsigned int)f2bf(f1.w) << 16);
        o1.x = (unsigned int)f2bf(f2.x) | ((unsigned int)f2bf(f2.y) << 16);
        o1.y = (unsigned int)f2bf(f2.z) | ((unsigned int)f2bf(f2.w) << 16);
        o1.z = (unsigned int)f2bf(f3.x) | ((unsigned int)f2bf(f3.y) << 16);
        o1.w = (unsigned int)f2bf(f3.z) | ((unsigned int)f2bf(f3.w) << 16);
        unsigned short* q = nb + (size_t)(row0 + r) * DIM + col0 + c;
        *(uint4*)q = o0;
        *(uint4*)(q + 8) = o1;
    }
    __syncthreads();
    {
        unsigned short v[16];
#pragma unroll
        for (int u = 0; u < 16; ++u) v[u] = f2bf(tile[c + u][r]);
        unsigned short* q = tr + (size_t)(col0 + r) * N_T + row0 + c;
        *(uint4*)q = *(uint4*)&v[0];
        *(uint4*)(q + 8) = *(uint4*)&v[8];
    }
}

// ---- fused projections: 128x64 tiles, 1024 blocks = 4/CU, 32 waves/CU ------
// C_bf16[4096][1024] = A_bf16 @ W_bf16^T + bias.  z: text / image.
__global__ void __launch_bounds__(256, 4)
gemm_proj2(const unsigned short* __restrict__ Atx, const unsigned short* __restrict__ Wtx,
           const float* __restrict__ btx, unsigned short* __restrict__ Ctx,
           const unsigned short* __restrict__ Aim, const unsigned short* __restrict__ Wim,
           const float* __restrict__ bim, unsigned short* __restrict__ Cim) {
    __shared__ unsigned short As[2][128 * 32];  // 16 KB
    __shared__ unsigned short Bs[2][64 * 32];   // 8 KB
    int z = blockIdx.z;
    const unsigned short* A = z ? Aim : Atx;
    const unsigned short* W = z ? Wim : Wtx;
    const float* bias = z ? bim : btx;
    unsigned short* C = z ? Cim : Ctx;
    int tid = threadIdx.x;
    int m0 = blockIdx.x * 128, n0 = blockIdx.y * 64;
    int lane = tid & 63, wave = tid >> 6;
    int lane16 = lane & 15, quad = lane >> 4;
    int wrow = (wave >> 1) * 64, wcol = (wave & 1) * 32;
    f32x4 acc[4][2];
    {
        f32x4 zz = {0.f, 0.f, 0.f, 0.f};
        for (int i = 0; i < 4; ++i)
            for (int j = 0; j < 2; ++j) acc[i][j] = zz;
    }
    for (int k0 = 0; k0 < DIM; k0 += 64) {
        stage_async(A, DIM, m0, k0, As[0], tid);
        stage_async64(W, DIM, n0, k0, Bs[0], tid);
        stage_async(A, DIM, m0, k0 + 32, As[1], tid);
        stage_async64(W, DIM, n0, k0 + 32, Bs[1], tid);
        __syncthreads();
        mfma_step42(As[0], Bs[0], acc, wrow, wcol, lane16, quad);
        mfma_step42(As[1], Bs[1], acc, wrow, wcol, lane16, quad);
        __syncthreads();
    }
#pragma unroll
    for (int j = 0; j < 2; ++j) {
        int col = n0 + wcol + j * 16 + lane16;
        float bv = bias[col];
#pragma unroll
        for (int i = 0; i < 4; ++i) {
            int rowb = m0 + wrow + i * 16 + quad * 4;
#pragma unroll
            for (int r = 0; r < 4; ++r)
                C[(size_t)(rowb + r) * DIM + col] = f2bf(acc[i][j][r] + bv);
        }
    }
}

// ---- logits+exp: P/PT bf16 (both layouts) + fused row/col exp-sums ---------
// r2-verified structure (128x128, 256 thr, 4 blk/CU) + XCD-aware remap:
// xcd = n>>2 -> each XCD owns a 4-wide n-band (B 1MB, L2-pinned) x all m
// (A read ~once per XCD). Wave-pair LDS pre-combine -> 1 atomic per row/col.
__global__ void __launch_bounds__(256, 4)
gemm_logits_exp(const unsigned short* __restrict__ Tb,
                const unsigned short* __restrict__ Ib,
                unsigned short* __restrict__ P, unsigned short* __restrict__ PT,
                float* __restrict__ lT, float* __restrict__ lI) {
    __shared__ unsigned short smem[128 * TSS];  // 34.8 KB: K-bufs + epilogue
    unsigned short* As0 = smem;
    unsigned short* Bs0 = smem + 4096;
    unsigned short* As1 = smem + 8192;
    unsigned short* Bs1 = smem + 12288;
    float* lred = (float*)(smem + 16384);  // 128 floats (free tail of smem)
    float* cred = lred + 128;              // 128 floats
    int tid = threadIdx.x;
    // XCD remap (physical p%8 = XCD heuristic): n = xcd*4 + (idx&3), m = idx>>2.
    int p = blockIdx.x + 32 * blockIdx.y;
    int xcd = p & 7, idx = p >> 3;
    int m0 = (idx >> 2) * 128, n0 = (xcd * 4 + (idx & 3)) * 128;
    int lane = tid & 63, wave = tid >> 6;
    int lane16 = lane & 15, quad = lane >> 4;
    int wrow = (wave >> 1) * 64, wcol = (wave & 1) * 64;
    f32x4 acc[4][4];
    {
        f32x4 z = {0.f, 0.f, 0.f, 0.f};
        for (int i = 0; i < 4; ++i)
            for (int j = 0; j < 4; ++j) acc[i][j] = z;
    }
    for (int k0 = 0; k0 < DIM; k0 += 64) {
        stage_async(Tb, DIM, m0, k0, As0, tid);
        stage_async(Ib, DIM, n0, k0, Bs0, tid);
        stage_async(Tb, DIM, m0, k0 + 32, As1, tid);
        stage_async(Ib, DIM, n0, k0 + 32, Bs1, tid);
        __syncthreads();
        mfma_step(As0, Bs0, acc, wrow, wcol, lane16, quad);
        mfma_step(As1, Bs1, acc, wrow, wcol, lane16, quad);
        __syncthreads();
    }
    // p = exp(logit/32) in place (fp32)
#pragma unroll
    for (int i = 0; i < 4; ++i)
#pragma unroll
        for (int j = 0; j < 4; ++j)
#pragma unroll
            for (int r = 0; r < 4; ++r)
                acc[i][j][r] = __expf(acc[i][j][r] * 0.03125f);
    // wave partials: rows (this wave's 64 cols) and cols (this wave's 64 rows)
    float rs[4][4];  // row partial, valid at lane16==0
#pragma unroll
    for (int i = 0; i < 4; ++i)
#pragma unroll
        for (int r = 0; r < 4; ++r) {
            float s = acc[i][0][r] + acc[i][1][r] + acc[i][2][r] + acc[i][3][r];
            s += __shfl_xor(s, 1); s += __shfl_xor(s, 2);
            s += __shfl_xor(s, 4); s += __shfl_xor(s, 8);
            rs[i][r] = s;
        }
    float cs[4];  // col partial, valid at quad==0
#pragma unroll
    for (int j = 0; j < 4; ++j) {
        float s = 0.f;
#pragma unroll
        for (int i = 0; i < 4; ++i)
#pragma unroll
            for (int r = 0; r < 4; ++r) s += acc[i][j][r];
        s += __shfl_xor(s, 16); s += __shfl_xor(s, 32);
        cs[j] = s;
    }
    // donors: waves 1,3 stash row partials; waves 2,3 stash col partials
    if (wave & 1) {
        if (lane16 == 0)
#pragma unroll
            for (int i = 0; i < 4; ++i)
#pragma unroll
                for (int r = 0; r < 4; ++r)
                    lred[wrow + i * 16 + quad * 4 + r] = rs[i][r];
    }
    if (wave >> 1) {
        if (quad == 0)
#pragma unroll
            for (int j = 0; j < 4; ++j)
                cred[wcol + j * 16 + lane16] = cs[j];
    }
    __syncthreads();
    // combiners: waves 0,2 finish rows; waves 0,1 finish cols
    if (!(wave & 1) && lane16 == 0) {
#pragma unroll
        for (int i = 0; i < 4; ++i)
#pragma unroll
            for (int r = 0; r < 4; ++r) {
                int row = wrow + i * 16 + quad * 4 + r;
                atomicAdd(&lT[m0 + row], rs[i][r] + lred[row]);
            }
    }
    if (!(wave >> 1) && quad == 0) {
#pragma unroll
        for (int j = 0; j < 4; ++j) {
            int col = wcol + j * 16 + lane16;
            atomicAdd(&lI[n0 + col], cs[j] + cred[col]);
        }
    }
    // pass 1: normal-layout tile -> P (coalesced b128 stores)
    __syncthreads();
#pragma unroll
    for (int i = 0; i < 4; ++i)
#pragma unroll
        for (int j = 0; j < 4; ++j)
#pragma unroll
            for (int r = 0; r < 4; ++r)
                smem[(wrow + i * 16 + quad * 4 + r) * TSS + wcol + j * 16 + lane16] =
                    f2bf(acc[i][j][r]);
    __syncthreads();
    tile_store(smem, P, N_I, m0, n0, tid);
    // pass 2: transposed tile -> PT (b64 LDS writes, coalesced b128 stores)
    __syncthreads();
#pragma unroll
    for (int i = 0; i < 4; ++i)
#pragma unroll
        for (int j = 0; j < 4; ++j) {
            unsigned int lo = (unsigned int)f2bf(acc[i][j][0]) |
                              ((unsigned int)f2bf(acc[i][j][1]) << 16);
            unsigned int hi = (unsigned int)f2bf(acc[i][j][2]) |
                              ((unsigned int)f2bf(acc[i][j][3]) << 16);
            uint2 v; v.x = lo; v.y = hi;
            *(uint2*)&smem[(wcol + j * 16 + lane16) * TSS + wrow + i * 16 + quad * 4] = v;
        }
    __syncthreads();
    tile_store(smem, PT, N_T, n0, m0, tid);
}

// ---- attn v3 (r2-verified) + XCD swizzle: 256x128, fine-phase pipeline -----
// grid (16, 8, 2), 512 thr, 144 KB dynamic LDS -> 1 block/CU, 8 waves.
// Tile protocol: {sub0; barrier; sub1; vmcnt(6)+lgkmcnt(0); barrier}.
// XCD remap: xcd = z*4 + n/2; within-XCD m-major with n-pair interleaved ->
// 2 B panels/XCD (L2-resident re-reads), A panels read pair-concurrently.
__global__ void __launch_bounds__(512)
gemm_attn3(const unsigned short* __restrict__ P, const unsigned short* __restrict__ imgT,
           const float* __restrict__ lT, const float* __restrict__ sTI,
           float* __restrict__ out0,
           const unsigned short* __restrict__ PT, const unsigned short* __restrict__ textT,
           const float* __restrict__ lI, const float* __restrict__ sIT,
           float* __restrict__ out1) {
    extern __shared__ unsigned short sm[];  // 3 * AT_SLOT shorts = 144 KB
    // XCD remap (p%8 = XCD heuristic): z = xcd>>2, n = (xcd&3)*2 + (idx&1),
    // m = idx>>1.  Bijective; correctness independent of actual mapping.
    int p = blockIdx.x + 16 * blockIdx.y + 128 * blockIdx.z;
    int xcd = p & 7, idx = p >> 3;
    int which = xcd >> 2;
    int m0 = (idx >> 1) * 256;
    int n0 = (((xcd & 3) << 1) | (idx & 1)) * 128;
    const unsigned short* A = which ? PT : P;
    const unsigned short* Bt = which ? textT : imgT;
    const float* l = which ? lI : lT;
    const float* sp = which ? sIT : sTI;
    float* out = which ? out1 : out0;

    int tid = threadIdx.x;
    int lane = tid & 63, wave = tid >> 6;
    int lane16 = lane & 15, quad = lane >> 4;
    int wrow = (wave >> 1) * 64, wcol = (wave & 1) * 64;  // 4M x 2N waves
    f32x4 acc[4][4];
    {
        f32x4 z = {0.f, 0.f, 0.f, 0.f};
        for (int i = 0; i < 4; ++i)
            for (int j = 0; j < 4; ++j) acc[i][j] = z;
    }

    // prologue: slots 0,1 <- tiles 0,1; vmcnt(6) leaves tile 1's 6 newest.
    at_stageA<4096>(A, m0, 0, sm, tid);
    at_stageB<4096>(Bt, n0, 0, sm + 16384, tid);
    at_stageA<4096>(A, m0, 64, sm + AT_SLOT, tid);
    at_stageB<4096>(Bt, n0, 64, sm + AT_SLOT + 16384, tid);
    asm volatile("s_waitcnt vmcnt(6)" ::: "memory");
    __builtin_amdgcn_s_barrier();

    int cur = 0;
    for (int s = 0; s < 62; ++s) {
        int ns = cur + 2; if (ns >= 3) ns -= 3;
        unsigned short* nsl = sm + ns * AT_SLOT;
        const unsigned short* cp = sm + cur * AT_SLOT;
        int kst = (s + 2) * 64;
        at_sub<4096, 1>(cp, A, Bt, m0, n0, kst, nsl, tid, acc, wrow, wcol, lane16, quad, 0);
        asm volatile("" ::: "memory");
        __builtin_amdgcn_s_barrier();
        asm volatile("" ::: "memory");
        at_sub<4096, 1>(cp, A, Bt, m0, n0, kst, nsl, tid, acc, wrow, wcol, lane16, quad, 1);
        asm volatile("s_waitcnt vmcnt(6) lgkmcnt(0)" ::: "memory");
        __builtin_amdgcn_s_barrier();
        cur += 1; if (cur >= 3) cur -= 3;
    }
    // tile 62 (no stage); end gate vmcnt(0): tile 63 fully landed.
    {
        const unsigned short* cp = sm + cur * AT_SLOT;
        at_sub<4096, 0>(cp, A, Bt, m0, n0, 0, nullptr, tid, acc, wrow, wcol, lane16, quad, 0);
        asm volatile("" ::: "memory");
        __builtin_amdgcn_s_barrier();
        asm volatile("" ::: "memory");
        at_sub<4096, 0>(cp, A, Bt, m0, n0, 0, nullptr, tid, acc, wrow, wcol, lane16, quad, 1);
        asm volatile("s_waitcnt vmcnt(0) lgkmcnt(0)" ::: "memory");
        __builtin_amdgcn_s_barrier();
        cur += 1; if (cur >= 3) cur -= 3;
    }
    // tile 63: compute only.
    {
        const unsigned short* cp = sm + cur * AT_SLOT;
        at_sub<4096, 0>(cp, A, Bt, m0, n0, 0, nullptr, tid, acc, wrow, wcol, lane16, quad, 0);
        at_sub<4096, 0>(cp, A, Bt, m0, n0, 0, nullptr, tid, acc, wrow, wcol, lane16, quad, 1);
    }

    float sc = sp[0];
#pragma unroll
    for (int i = 0; i < 4; ++i) {
        int rowb = m0 + wrow + i * 16 + quad * 4;
        float fac[4];
#pragma unroll
        for (int r = 0; r < 4; ++r) fac[r] = sc / l[rowb + r];
#pragma unroll
        for (int j = 0; j < 4; ++j) {
            int col = n0 + wcol + j * 16 + lane16;
#pragma unroll
            for (int r = 0; r < 4; ++r)
                out[(size_t)(rowb + r) * DIM + col] = acc[i][j][r] * fac[r];
        }
    }
}

extern "C" void kernel_launch(void* const* d_in, const int* in_sizes, int n_in,
                              void* d_out, int out_size, void* d_ws, size_t ws_size,
                              hipStream_t stream) {
    const float* text = (const float*)d_in[0];
    const float* image = (const float*)d_in[1];
    const float* w_text = (const float*)d_in[2];
    const float* b_text = (const float*)d_in[3];
    const float* w_image = (const float*)d_in[4];
    const float* b_image = (const float*)d_in[5];
    const float* scale_TI = (const float*)d_in[6];
    const float* scale_IT = (const float*)d_in[7];
    float* out0 = (float*)d_out;
    float* out1 = out0 + (size_t)N_T * DIM;

    // Workspace layout (96 MB + 32 KB). cvt buffers [0,20MB) die after proj2;
    // gemm_logits_exp then writes P over [0,32MB) — lifetimes disjoint.
    char* ws = (char*)d_ws;
    unsigned short* text_bf = (unsigned short*)(ws);                 // 8 MB  (dies after proj)
    unsigned short* image_bf = (unsigned short*)(ws + (8ull << 20)); // 8 MB  (dies after proj)
    unsigned short* wt_bf = (unsigned short*)(ws + (16ull << 20));   // 2 MB  (dies after proj)
    unsigned short* wi_bf = (unsigned short*)(ws + (18ull << 20));   // 2 MB  (dies after proj)
    unsigned short* P = (unsigned short*)(ws);                       // 32 MB (logits -> attn)
    unsigned short* imgT = (unsigned short*)(ws + (32ull << 20));    // 8 MB
    unsigned short* textT = (unsigned short*)(ws + (40ull << 20));   // 8 MB
    unsigned short* t_bf = (unsigned short*)(ws + (48ull << 20));    // 8 MB
    unsigned short* i_bf = (unsigned short*)(ws + (56ull << 20));    // 8 MB
    unsigned short* PT = (unsigned short*)(ws + (64ull << 20));      // 32 MB
    float* lT = (float*)(ws + (96ull << 20));                        // 16 KB
    float* lI = (float*)(ws + (96ull << 20) + 16384);                // 16 KB

    // 144 KB dynamic LDS for gemm_attn3 (one-time host attribute; safe under
    // graph capture).
    static bool lds_set = false;
    if (!lds_set) {
        hipFuncSetAttribute((const void*)gemm_attn3,
                            hipFuncAttributeMaxDynamicSharedMemorySize, AT_LDS_BYTES);
        lds_set = true;
    }

    // z=0/1: feature 64x64 cvt+transpose tiles; z=2: weights cvt + lT/lI zero.
    cvt_all<<<dim3(N_T / 64, DIM / 64, 3), 256, 0, stream>>>(
        image, text, w_text, w_image, image_bf, text_bf, imgT, textT,
        wt_bf, wi_bf, lT);

    gemm_proj2<<<dim3(N_T / 128, DIM / 64, 2), 256, 0, stream>>>(
        text_bf, wt_bf, b_text, t_bf, image_bf, wi_bf, b_image, i_bf);

    gemm_logits_exp<<<dim3(N_T / 128, N_I / 128), 256, 0, stream>>>(t_bf, i_bf, P, PT, lT, lI);

    gemm_attn3<<<dim3(N_T / 256, DIM / 128, 2), 512, AT_LDS_BYTES, stream>>>(
        P, imgT, lT, scale_TI, out0, PT, textT, lI, scale_IT, out1);
}

// Round 6
// 245.582 us; speedup vs baseline: 1.3637x; 1.0238x over previous
//
#include <hip/hip_runtime.h>

// ---------------------------------------------------------------------------
// ImageTextModule: dual cross-attention between text and image feature sets.
//   t = text @ w_text^T + b_text ; i = image @ w_image^T + b_image  (bf16)
//   P  = exp((t @ i^T) / 32)  materialized ONCE in bf16, BOTH layouts (P, PT);
//        row/col exp-sums fused (wave-pair LDS pre-combine -> 1 atomic per
//        row/col per block).
//   out0 = (scale_TI / lT) * P  @ image ; out1 = (scale_IT / lI) * PT @ text
// attn (v3, r2-verified, swizzle REVERTED): fine-phase counted-vmcnt pipeline.
//   256x128 tile, 512 thr / 8 waves (4Mx2N, wave 64x64, acc[4][4]); per
//   BK=64 tile: two sub-phases {8 ds_read + 3-gload stage-half + setprio'd
//   16 MFMA + barrier}; vmcnt(6)+lgkmcnt(0) gate once per tile; 3-slot LDS
//   ring (144 KB dynamic). chunk16 ^= (row&7) swizzle on BOTH gload source
//   (inverse) and ds_read addr -> conflicts 0. Measured r2: 68.2 µs.
//   FAILED structural attacks (do not retry): A-from-global regs (r4: 158 µs,
//   +66% traffic); XCD block remap (r5: 73.8 µs, FETCH 98->139 MB — working
//   set is L3-fit, remap breaks natural sharing and ADDS HBM traffic).
// proj (v3, THIS round): the verified attn3 pipeline, parameters only:
//   LD=1024, K=1024 (16 tiles), bias epilogue. 256x128 tiles, grid
//   (16,8,2)=256 blocks=1/CU. Epilogue is tiny (bias + 64KB store) so the
//   r3 1-blk/CU-epilogue failure mode does not apply.
// logits: r2-verified 128x128/256thr/4blk-CU. DO NOT re-port the 1-blk/CU
//   pipeline (r3: 81 µs — its big epilogue needs occupancy overlap).
// Workspace: 96 MB + 32 KB.
// ---------------------------------------------------------------------------

typedef __bf16 bf16x8 __attribute__((ext_vector_type(8)));
typedef float f32x4 __attribute__((ext_vector_type(4)));

#define N_T 4096
#define N_I 4096
#define DIM 1024
#define TSS 136  // epilogue tile stride (bf16): 128 + 8 pad

// ring slot: A 256x64 bf16 (16384 sh) + B 128x64 bf16 (8192 sh) = 48 KB
#define AT_SLOT 24576
#define AT_LDS_BYTES (3 * AT_SLOT * 2)  // 147456 B = 144 KB

__device__ __forceinline__ unsigned short f2bf(float f) {
    unsigned int u = __float_as_uint(f);
    u += 0x7fffu + ((u >> 16) & 1u);  // RNE
    return (unsigned short)(u >> 16);
}

// 16-byte async global->LDS DMA (no VGPR round-trip).
__device__ __forceinline__ void async_cp16(const unsigned short* g, unsigned short* l) {
    __builtin_amdgcn_global_load_lds(
        (const __attribute__((address_space(1))) unsigned int*)g,
        (__attribute__((address_space(3))) unsigned int*)l, 16, 0, 0);
}

// Stage 128x32 bf16 tile -> unpadded LDS [128][32] with 256 threads.
__device__ __forceinline__ void stage_async(const unsigned short* __restrict__ src,
                                            int ld, int row0, int k0,
                                            unsigned short* lds, int t) {
    int r = t >> 2, c = (t & 3) << 3;
    const unsigned short* g = src + (size_t)(row0 + r) * ld + k0 + c;
    async_cp16(g, lds + r * 32 + c);
    async_cp16(g + (size_t)64 * ld, lds + (64 + r) * 32 + c);
}

// One BK=32 MFMA step, 4x4 frags (64x64 wave tile) — logits kernel.
__device__ __forceinline__ void mfma_step(const unsigned short* As,
                                          const unsigned short* Bs, f32x4 acc[4][4],
                                          int wrow, int wcol, int lane16, int quad) {
    bf16x8 a[4], b[4];
#pragma unroll
    for (int i = 0; i < 4; ++i) {
        a[i] = *(const bf16x8*)&As[(wrow + i * 16 + lane16) * 32 + quad * 8];
        b[i] = *(const bf16x8*)&Bs[(wcol + i * 16 + lane16) * 32 + quad * 8];
    }
#pragma unroll
    for (int i = 0; i < 4; ++i)
#pragma unroll
        for (int j = 0; j < 4; ++j)
            acc[i][j] = __builtin_amdgcn_mfma_f32_16x16x32_bf16(a[i], b[j], acc[i][j], 0, 0, 0);
}

// Coalesced 128x128 bf16 tile store from LDS (stride TSS) to global.
__device__ __forceinline__ void tile_store(const unsigned short* sm,
                                           unsigned short* __restrict__ g, int ld,
                                           int row0, int col0, int tid) {
    int r = tid >> 1, h = (tid & 1) << 6;
    const unsigned short* src = sm + r * TSS + h;
    unsigned short* dst = g + (size_t)(row0 + r) * ld + col0 + h;
#pragma unroll
    for (int v = 0; v < 8; ++v)
        *(uint4*)(dst + v * 8) = *(const uint4*)(src + v * 8);
}

// ---- fine-phase pipeline stagers (attn + proj) -----------------------------
// LDS ring slot: A [256][64] bf16 (chunk16-swizzled), B [128][64].
// Swizzle: 16B-chunk index within a row ^= (row & 7) -> conflict-free
// (measured 0). Applied BOTH at the gload source (inverse) and ds_read addr.

// Stage A half h (128 rows, 1024 chunks, 2 per thread; LDS dest linear).
template <int LD>
__device__ __forceinline__ void at_stageA_half(const unsigned short* __restrict__ g,
                                               int row0, int k0, unsigned short* lds,
                                               int t, int h) {
#pragma unroll
    for (int u = 0; u < 2; ++u) {
        int c = t + (h * 2 + u) * 512;
        int r = c >> 3;
        int kq = (c & 7) ^ (r & 7);  // inverse-swizzled global chunk
        async_cp16(g + (size_t)(row0 + r) * LD + k0 + (kq << 3), lds + c * 8);
    }
}

// Stage B half h (64 rows, 512 chunks, 1 per thread).
template <int LD>
__device__ __forceinline__ void at_stageB_half(const unsigned short* __restrict__ g,
                                               int row0, int k0, unsigned short* lds,
                                               int t, int h) {
    int c = t + h * 512;
    int r = c >> 3;
    int kq = (c & 7) ^ (r & 7);
    async_cp16(g + (size_t)(row0 + r) * LD + k0 + (kq << 3), lds + c * 8);
}

// Full-tile stagers (prologue only).
template <int LD>
__device__ __forceinline__ void at_stageA(const unsigned short* __restrict__ g,
                                          int row0, int k0, unsigned short* lds, int t) {
    at_stageA_half<LD>(g, row0, k0, lds, t, 0);
    at_stageA_half<LD>(g, row0, k0, lds, t, 1);
}
template <int LD>
__device__ __forceinline__ void at_stageB(const unsigned short* __restrict__ g,
                                          int row0, int k0, unsigned short* lds, int t) {
    at_stageB_half<LD>(g, row0, k0, lds, t, 0);
    at_stageB_half<LD>(g, row0, k0, lds, t, 1);
}

// One sub-phase: 8 swizzled ds_read_b128 (K-slice ks of slot cp) + stage-half
// ks of tile s+2 into nsl + 16 MFMA under setprio(1). 16-MFMA grain = the
// m196/m201-proven interleave unit; compiler inserts fine lgkmcnt for the
// read->MFMA deps (no manual waits inside -> rule-18 safe).
template <int LD, int DO_STAGE>
__device__ __forceinline__ void at_sub(const unsigned short* cp,
                                       const unsigned short* __restrict__ A,
                                       const unsigned short* __restrict__ Bt,
                                       int m0, int n0, int kst, unsigned short* nsl,
                                       int t, f32x4 acc[4][4],
                                       int wrow, int wcol, int lane16, int quad, int ks) {
    const unsigned short* As = cp;
    const unsigned short* Bs = cp + 16384;
    bf16x8 a[4], b[4];
    int sw = (((ks << 2) | quad) ^ (lane16 & 7)) << 3;  // row&7 == lane16&7
#pragma unroll
    for (int i = 0; i < 4; ++i)
        a[i] = *(const bf16x8*)&As[(wrow + i * 16 + lane16) * 64 + sw];
#pragma unroll
    for (int j = 0; j < 4; ++j)
        b[j] = *(const bf16x8*)&Bs[(wcol + j * 16 + lane16) * 64 + sw];
    if (DO_STAGE) {
        at_stageA_half<LD>(A, m0, kst, nsl, t, ks);
        at_stageB_half<LD>(Bt, n0, kst, nsl + 16384, t, ks);
    }
    __builtin_amdgcn_s_setprio(1);
#pragma unroll
    for (int i = 0; i < 4; ++i)
#pragma unroll
        for (int j = 0; j < 4; ++j)
            acc[i][j] = __builtin_amdgcn_mfma_f32_16x16x32_bf16(a[i], b[j], acc[i][j], 0, 0, 0);
    __builtin_amdgcn_s_setprio(0);
}

// ---- unified pre-pass ------------------------------------------------------
// z=0: image 64x64 tile -> image_bf + imgT      z=1: text -> text_bf + textT
// z=2: weights flat cvt (lin id over 1024 blocks); blocks 0-3 zero lT/lI.
__global__ void __launch_bounds__(256)
cvt_all(const float* __restrict__ im, const float* __restrict__ tx,
        const float* __restrict__ wt, const float* __restrict__ wi,
        unsigned short* __restrict__ imb, unsigned short* __restrict__ txb,
        unsigned short* __restrict__ imgT, unsigned short* __restrict__ textT,
        unsigned short* __restrict__ wtb, unsigned short* __restrict__ wib,
        float* __restrict__ lTI) {
    int t = threadIdx.x;
    if (blockIdx.z == 2) {
        int lin = blockIdx.y * 64 + blockIdx.x;  // 0..1023
        if (lin < 4) {
            *(f32x4*)&lTI[(lin * 256 + t) * 8] = (f32x4){0.f, 0.f, 0.f, 0.f};
            *(f32x4*)&lTI[(lin * 256 + t) * 8 + 4] = (f32x4){0.f, 0.f, 0.f, 0.f};
        }
        size_t i = (size_t)(lin * 256 + t) * 8;
        const float* s;
        unsigned short* d;
        size_t off;
        if (i < 1048576) { s = wt; d = wtb; off = i; }
        else             { s = wi; d = wib; off = i - 1048576; }
        float4 f0 = *(const float4*)(s + off);
        float4 f1 = *(const float4*)(s + off + 4);
        uint4 o;
        o.x = (unsigned int)f2bf(f0.x) | ((unsigned int)f2bf(f0.y) << 16);
        o.y = (unsigned int)f2bf(f0.z) | ((unsigned int)f2bf(f0.w) << 16);
        o.z = (unsigned int)f2bf(f1.x) | ((unsigned int)f2bf(f1.y) << 16);
        o.w = (unsigned int)f2bf(f1.z) | ((unsigned int)f2bf(f1.w) << 16);
        *(uint4*)(d + off) = o;
        return;
    }
    const float* in = blockIdx.z ? tx : im;
    unsigned short* nb = blockIdx.z ? txb : imb;
    unsigned short* tr = blockIdx.z ? textT : imgT;
    __shared__ float tile[64][65];
    int row0 = blockIdx.x * 64, col0 = blockIdx.y * 64;
    int r = t >> 2, c = (t & 3) << 4;  // 64 rows x 4 col-chunks of 16
    {
        const float* p = in + (size_t)(row0 + r) * DIM + col0 + c;
        float4 f0 = *(const float4*)(p);
        float4 f1 = *(const float4*)(p + 4);
        float4 f2 = *(const float4*)(p + 8);
        float4 f3 = *(const float4*)(p + 12);
        *(float4*)&tile[r][c] = f0;
        *(float4*)&tile[r][c + 4] = f1;
        *(float4*)&tile[r][c + 8] = f2;
        *(float4*)&tile[r][c + 12] = f3;
        uint4 o0, o1;
        o0.x = (unsigned int)f2bf(f0.x) | ((unsigned int)f2bf(f0.y) << 16);
        o0.y = (unsigned int)f2bf(f0.z) | ((unsigned int)f2bf(f0.w) << 16);
        o0.z = (unsigned int)f2bf(f1.x) | ((unsigned int)f2bf(f1.y) << 16);
        o0.w = (unsigned int)f2bf(f1.z) | ((unsigned int)f2bf(f1.w) << 16);
        o1.x = (unsigned int)f2bf(f2.x) | ((unsigned int)f2bf(f2.y) << 16);
        o1.y = (unsigned int)f2bf(f2.z) | ((unsigned int)f2bf(f2.w) << 16);
        o1.z = (unsigned int)f2bf(f3.x) | ((unsigned int)f2bf(f3.y) << 16);
        o1.w = (unsigned int)f2bf(f3.z) | ((unsigned int)f2bf(f3.w) << 16);
        unsigned short* q = nb + (size_t)(row0 + r) * DIM + col0 + c;
        *(uint4*)q = o0;
        *(uint4*)(q + 8) = o1;
    }
    __syncthreads();
    {
        unsigned short v[16];
#pragma unroll
        for (int u = 0; u < 16; ++u) v[u] = f2bf(tile[c + u][r]);
        unsigned short* q = tr + (size_t)(col0 + r) * N_T + row0 + c;
        *(uint4*)q = *(uint4*)&v[0];
        *(uint4*)(q + 8) = *(uint4*)&v[8];
    }
}

// ---- proj v3: fine-phase pipeline, 256x128 tiles, bias epilogue ------------
// C_bf16[4096][1024] = A_bf16 @ W_bf16^T + bias.  grid (16, 8, 2), 512 thr,
// 144 KB dynamic LDS -> 1 blk/CU. K=1024 -> 16 tiles: 14 staged + 2 peeled.
// Identical ring/gates/swizzle to attn3 (verified structure; params only).
__global__ void __launch_bounds__(512)
gemm_proj3(const unsigned short* __restrict__ Atx, const unsigned short* __restrict__ Wtx,
           const float* __restrict__ btx, unsigned short* __restrict__ Ctx,
           const unsigned short* __restrict__ Aim, const unsigned short* __restrict__ Wim,
           const float* __restrict__ bim, unsigned short* __restrict__ Cim) {
    extern __shared__ unsigned short sm[];  // 3 * AT_SLOT shorts = 144 KB
    int z = blockIdx.z;
    const unsigned short* A = z ? Aim : Atx;
    const unsigned short* W = z ? Wim : Wtx;
    const float* bias = z ? bim : btx;
    unsigned short* C = z ? Cim : Ctx;

    int tid = threadIdx.x;
    int m0 = blockIdx.x * 256, n0 = blockIdx.y * 128;
    int lane = tid & 63, wave = tid >> 6;
    int lane16 = lane & 15, quad = lane >> 4;
    int wrow = (wave >> 1) * 64, wcol = (wave & 1) * 64;  // 4M x 2N waves
    f32x4 acc[4][4];
    {
        f32x4 zz = {0.f, 0.f, 0.f, 0.f};
        for (int i = 0; i < 4; ++i)
            for (int j = 0; j < 4; ++j) acc[i][j] = zz;
    }

    // prologue: slots 0,1 <- tiles 0,1; vmcnt(6) leaves tile 1's 6 newest.
    at_stageA<DIM>(A, m0, 0, sm, tid);
    at_stageB<DIM>(W, n0, 0, sm + 16384, tid);
    at_stageA<DIM>(A, m0, 64, sm + AT_SLOT, tid);
    at_stageB<DIM>(W, n0, 64, sm + AT_SLOT + 16384, tid);
    asm volatile("s_waitcnt vmcnt(6)" ::: "memory");
    __builtin_amdgcn_s_barrier();

    int cur = 0;
    for (int s = 0; s < 14; ++s) {  // DIM/64 - 2 pipelined tiles
        int ns = cur + 2; if (ns >= 3) ns -= 3;
        unsigned short* nsl = sm + ns * AT_SLOT;
        const unsigned short* cp = sm + cur * AT_SLOT;
        int kst = (s + 2) * 64;
        at_sub<DIM, 1>(cp, A, W, m0, n0, kst, nsl, tid, acc, wrow, wcol, lane16, quad, 0);
        asm volatile("" ::: "memory");
        __builtin_amdgcn_s_barrier();
        asm volatile("" ::: "memory");
        at_sub<DIM, 1>(cp, A, W, m0, n0, kst, nsl, tid, acc, wrow, wcol, lane16, quad, 1);
        asm volatile("s_waitcnt vmcnt(6) lgkmcnt(0)" ::: "memory");
        __builtin_amdgcn_s_barrier();
        cur += 1; if (cur >= 3) cur -= 3;
    }
    // tile 14 (no stage); end gate vmcnt(0): tile 15 fully landed.
    {
        const unsigned short* cp = sm + cur * AT_SLOT;
        at_sub<DIM, 0>(cp, A, W, m0, n0, 0, nullptr, tid, acc, wrow, wcol, lane16, quad, 0);
        asm volatile("" ::: "memory");
        __builtin_amdgcn_s_barrier();
        asm volatile("" ::: "memory");
        at_sub<DIM, 0>(cp, A, W, m0, n0, 0, nullptr, tid, acc, wrow, wcol, lane16, quad, 1);
        asm volatile("s_waitcnt vmcnt(0) lgkmcnt(0)" ::: "memory");
        __builtin_amdgcn_s_barrier();
        cur += 1; if (cur >= 3) cur -= 3;
    }
    // tile 15: compute only.
    {
        const unsigned short* cp = sm + cur * AT_SLOT;
        at_sub<DIM, 0>(cp, A, W, m0, n0, 0, nullptr, tid, acc, wrow, wcol, lane16, quad, 0);
        at_sub<DIM, 0>(cp, A, W, m0, n0, 0, nullptr, tid, acc, wrow, wcol, lane16, quad, 1);
    }

#pragma unroll
    for (int j = 0; j < 4; ++j) {
        int col = n0 + wcol + j * 16 + lane16;
        float bv = bias[col];
#pragma unroll
        for (int i = 0; i < 4; ++i) {
            int rowb = m0 + wrow + i * 16 + quad * 4;
#pragma unroll
            for (int r = 0; r < 4; ++r)
                C[(size_t)(rowb + r) * DIM + col] = f2bf(acc[i][j][r] + bv);
        }
    }
}

// ---- logits+exp: P/PT bf16 (both layouts) + fused row/col exp-sums ---------
// r2-verified structure (128x128, 256 thr, 4 blk/CU). Wave-pair LDS
// pre-combine -> one atomic per row/col per block.
__global__ void __launch_bounds__(256, 4)
gemm_logits_exp(const unsigned short* __restrict__ Tb,
                const unsigned short* __restrict__ Ib,
                unsigned short* __restrict__ P, unsigned short* __restrict__ PT,
                float* __restrict__ lT, float* __restrict__ lI) {
    __shared__ unsigned short smem[128 * TSS];  // 34.8 KB: K-bufs + epilogue
    unsigned short* As0 = smem;
    unsigned short* Bs0 = smem + 4096;
    unsigned short* As1 = smem + 8192;
    unsigned short* Bs1 = smem + 12288;
    float* lred = (float*)(smem + 16384);  // 128 floats (free tail of smem)
    float* cred = lred + 128;              // 128 floats
    int tid = threadIdx.x;
    int m0 = blockIdx.x * 128, n0 = blockIdx.y * 128;
    int lane = tid & 63, wave = tid >> 6;
    int lane16 = lane & 15, quad = lane >> 4;
    int wrow = (wave >> 1) * 64, wcol = (wave & 1) * 64;
    f32x4 acc[4][4];
    {
        f32x4 z = {0.f, 0.f, 0.f, 0.f};
        for (int i = 0; i < 4; ++i)
            for (int j = 0; j < 4; ++j) acc[i][j] = z;
    }
    for (int k0 = 0; k0 < DIM; k0 += 64) {
        stage_async(Tb, DIM, m0, k0, As0, tid);
        stage_async(Ib, DIM, n0, k0, Bs0, tid);
        stage_async(Tb, DIM, m0, k0 + 32, As1, tid);
        stage_async(Ib, DIM, n0, k0 + 32, Bs1, tid);
        __syncthreads();
        mfma_step(As0, Bs0, acc, wrow, wcol, lane16, quad);
        mfma_step(As1, Bs1, acc, wrow, wcol, lane16, quad);
        __syncthreads();
    }
    // p = exp(logit/32) in place (fp32)
#pragma unroll
    for (int i = 0; i < 4; ++i)
#pragma unroll
        for (int j = 0; j < 4; ++j)
#pragma unroll
            for (int r = 0; r < 4; ++r)
                acc[i][j][r] = __expf(acc[i][j][r] * 0.03125f);
    // wave partials: rows (this wave's 64 cols) and cols (this wave's 64 rows)
    float rs[4][4];  // row partial, valid at lane16==0
#pragma unroll
    for (int i = 0; i < 4; ++i)
#pragma unroll
        for (int r = 0; r < 4; ++r) {
            float s = acc[i][0][r] + acc[i][1][r] + acc[i][2][r] + acc[i][3][r];
            s += __shfl_xor(s, 1); s += __shfl_xor(s, 2);
            s += __shfl_xor(s, 4); s += __shfl_xor(s, 8);
            rs[i][r] = s;
        }
    float cs[4];  // col partial, valid at quad==0
#pragma unroll
    for (int j = 0; j < 4; ++j) {
        float s = 0.f;
#pragma unroll
        for (int i = 0; i < 4; ++i)
#pragma unroll
            for (int r = 0; r < 4; ++r) s += acc[i][j][r];
        s += __shfl_xor(s, 16); s += __shfl_xor(s, 32);
        cs[j] = s;
    }
    // donors: waves 1,3 stash row partials; waves 2,3 stash col partials
    if (wave & 1) {
        if (lane16 == 0)
#pragma unroll
            for (int i = 0; i < 4; ++i)
#pragma unroll
                for (int r = 0; r < 4; ++r)
                    lred[wrow + i * 16 + quad * 4 + r] = rs[i][r];
    }
    if (wave >> 1) {
        if (quad == 0)
#pragma unroll
            for (int j = 0; j < 4; ++j)
                cred[wcol + j * 16 + lane16] = cs[j];
    }
    __syncthreads();
    // combiners: waves 0,2 finish rows; waves 0,1 finish cols
    if (!(wave & 1) && lane16 == 0) {
#pragma unroll
        for (int i = 0; i < 4; ++i)
#pragma unroll
            for (int r = 0; r < 4; ++r) {
                int row = wrow + i * 16 + quad * 4 + r;
                atomicAdd(&lT[m0 + row], rs[i][r] + lred[row]);
            }
    }
    if (!(wave >> 1) && quad == 0) {
#pragma unroll
        for (int j = 0; j < 4; ++j) {
            int col = wcol + j * 16 + lane16;
            atomicAdd(&lI[n0 + col], cs[j] + cred[col]);
        }
    }
    // pass 1: normal-layout tile -> P (coalesced b128 stores)
    __syncthreads();
#pragma unroll
    for (int i = 0; i < 4; ++i)
#pragma unroll
        for (int j = 0; j < 4; ++j)
#pragma unroll
            for (int r = 0; r < 4; ++r)
                smem[(wrow + i * 16 + quad * 4 + r) * TSS + wcol + j * 16 + lane16] =
                    f2bf(acc[i][j][r]);
    __syncthreads();
    tile_store(smem, P, N_I, m0, n0, tid);
    // pass 2: transposed tile -> PT (b64 LDS writes, coalesced b128 stores)
    __syncthreads();
#pragma unroll
    for (int i = 0; i < 4; ++i)
#pragma unroll
        for (int j = 0; j < 4; ++j) {
            unsigned int lo = (unsigned int)f2bf(acc[i][j][0]) |
                              ((unsigned int)f2bf(acc[i][j][1]) << 16);
            unsigned int hi = (unsigned int)f2bf(acc[i][j][2]) |
                              ((unsigned int)f2bf(acc[i][j][3]) << 16);
            uint2 v; v.x = lo; v.y = hi;
            *(uint2*)&smem[(wcol + j * 16 + lane16) * TSS + wrow + i * 16 + quad * 4] = v;
        }
    __syncthreads();
    tile_store(smem, PT, N_T, n0, m0, tid);
}

// ---- attn v3 (r2-verified, natural block order): fine-phase pipeline -------
// grid (16, 8, 2), 512 thr, 144 KB dynamic LDS -> 1 block/CU, 8 waves.
// Tile protocol: {sub0; barrier; sub1; vmcnt(6)+lgkmcnt(0); barrier}.
__global__ void __launch_bounds__(512)
gemm_attn3(const unsigned short* __restrict__ P, const unsigned short* __restrict__ imgT,
           const float* __restrict__ lT, const float* __restrict__ sTI,
           float* __restrict__ out0,
           const unsigned short* __restrict__ PT, const unsigned short* __restrict__ textT,
           const float* __restrict__ lI, const float* __restrict__ sIT,
           float* __restrict__ out1) {
    extern __shared__ unsigned short sm[];  // 3 * AT_SLOT shorts = 144 KB
    int which = blockIdx.z;
    const unsigned short* A = which ? PT : P;
    const unsigned short* Bt = which ? textT : imgT;
    const float* l = which ? lI : lT;
    const float* sp = which ? sIT : sTI;
    float* out = which ? out1 : out0;

    int tid = threadIdx.x;
    int m0 = blockIdx.x * 256, n0 = blockIdx.y * 128;
    int lane = tid & 63, wave = tid >> 6;
    int lane16 = lane & 15, quad = lane >> 4;
    int wrow = (wave >> 1) * 64, wcol = (wave & 1) * 64;  // 4M x 2N waves
    f32x4 acc[4][4];
    {
        f32x4 z = {0.f, 0.f, 0.f, 0.f};
        for (int i = 0; i < 4; ++i)
            for (int j = 0; j < 4; ++j) acc[i][j] = z;
    }

    // prologue: slots 0,1 <- tiles 0,1; vmcnt(6) leaves tile 1's 6 newest.
    at_stageA<4096>(A, m0, 0, sm, tid);
    at_stageB<4096>(Bt, n0, 0, sm + 16384, tid);
    at_stageA<4096>(A, m0, 64, sm + AT_SLOT, tid);
    at_stageB<4096>(Bt, n0, 64, sm + AT_SLOT + 16384, tid);
    asm volatile("s_waitcnt vmcnt(6)" ::: "memory");
    __builtin_amdgcn_s_barrier();

    int cur = 0;
    for (int s = 0; s < 62; ++s) {
        int ns = cur + 2; if (ns >= 3) ns -= 3;
        unsigned short* nsl = sm + ns * AT_SLOT;
        const unsigned short* cp = sm + cur * AT_SLOT;
        int kst = (s + 2) * 64;
        at_sub<4096, 1>(cp, A, Bt, m0, n0, kst, nsl, tid, acc, wrow, wcol, lane16, quad, 0);
        asm volatile("" ::: "memory");
        __builtin_amdgcn_s_barrier();
        asm volatile("" ::: "memory");
        at_sub<4096, 1>(cp, A, Bt, m0, n0, kst, nsl, tid, acc, wrow, wcol, lane16, quad, 1);
        asm volatile("s_waitcnt vmcnt(6) lgkmcnt(0)" ::: "memory");
        __builtin_amdgcn_s_barrier();
        cur += 1; if (cur >= 3) cur -= 3;
    }
    // tile 62 (no stage); end gate vmcnt(0): tile 63 fully landed.
    {
        const unsigned short* cp = sm + cur * AT_SLOT;
        at_sub<4096, 0>(cp, A, Bt, m0, n0, 0, nullptr, tid, acc, wrow, wcol, lane16, quad, 0);
        asm volatile("" ::: "memory");
        __builtin_amdgcn_s_barrier();
        asm volatile("" ::: "memory");
        at_sub<4096, 0>(cp, A, Bt, m0, n0, 0, nullptr, tid, acc, wrow, wcol, lane16, quad, 1);
        asm volatile("s_waitcnt vmcnt(0) lgkmcnt(0)" ::: "memory");
        __builtin_amdgcn_s_barrier();
        cur += 1; if (cur >= 3) cur -= 3;
    }
    // tile 63: compute only.
    {
        const unsigned short* cp = sm + cur * AT_SLOT;
        at_sub<4096, 0>(cp, A, Bt, m0, n0, 0, nullptr, tid, acc, wrow, wcol, lane16, quad, 0);
        at_sub<4096, 0>(cp, A, Bt, m0, n0, 0, nullptr, tid, acc, wrow, wcol, lane16, quad, 1);
    }

    float sc = sp[0];
#pragma unroll
    for (int i = 0; i < 4; ++i) {
        int rowb = m0 + wrow + i * 16 + quad * 4;
        float fac[4];
#pragma unroll
        for (int r = 0; r < 4; ++r) fac[r] = sc / l[rowb + r];
#pragma unroll
        for (int j = 0; j < 4; ++j) {
            int col = n0 + wcol + j * 16 + lane16;
#pragma unroll
            for (int r = 0; r < 4; ++r)
                out[(size_t)(rowb + r) * DIM + col] = acc[i][j][r] * fac[r];
        }
    }
}

extern "C" void kernel_launch(void* const* d_in, const int* in_sizes, int n_in,
                              void* d_out, int out_size, void* d_ws, size_t ws_size,
                              hipStream_t stream) {
    const float* text = (const float*)d_in[0];
    const float* image = (const float*)d_in[1];
    const float* w_text = (const float*)d_in[2];
    const float* b_text = (const float*)d_in[3];
    const float* w_image = (const float*)d_in[4];
    const float* b_image = (const float*)d_in[5];
    const float* scale_TI = (const float*)d_in[6];
    const float* scale_IT = (const float*)d_in[7];
    float* out0 = (float*)d_out;
    float* out1 = out0 + (size_t)N_T * DIM;

    // Workspace layout (96 MB + 32 KB). cvt buffers [0,20MB) die after proj;
    // gemm_logits_exp then writes P over [0,32MB) — lifetimes disjoint.
    char* ws = (char*)d_ws;
    unsigned short* text_bf = (unsigned short*)(ws);                 // 8 MB  (dies after proj)
    unsigned short* image_bf = (unsigned short*)(ws + (8ull << 20)); // 8 MB  (dies after proj)
    unsigned short* wt_bf = (unsigned short*)(ws + (16ull << 20));   // 2 MB  (dies after proj)
    unsigned short* wi_bf = (unsigned short*)(ws + (18ull << 20));   // 2 MB  (dies after proj)
    unsigned short* P = (unsigned short*)(ws);                       // 32 MB (logits -> attn)
    unsigned short* imgT = (unsigned short*)(ws + (32ull << 20));    // 8 MB
    unsigned short* textT = (unsigned short*)(ws + (40ull << 20));   // 8 MB
    unsigned short* t_bf = (unsigned short*)(ws + (48ull << 20));    // 8 MB
    unsigned short* i_bf = (unsigned short*)(ws + (56ull << 20));    // 8 MB
    unsigned short* PT = (unsigned short*)(ws + (64ull << 20));      // 32 MB
    float* lT = (float*)(ws + (96ull << 20));                        // 16 KB
    float* lI = (float*)(ws + (96ull << 20) + 16384);                // 16 KB

    // 144 KB dynamic LDS (one-time host attribute; safe under graph capture).
    static bool lds_set = false;
    if (!lds_set) {
        hipFuncSetAttribute((const void*)gemm_attn3,
                            hipFuncAttributeMaxDynamicSharedMemorySize, AT_LDS_BYTES);
        hipFuncSetAttribute((const void*)gemm_proj3,
                            hipFuncAttributeMaxDynamicSharedMemorySize, AT_LDS_BYTES);
        lds_set = true;
    }

    // z=0/1: feature 64x64 cvt+transpose tiles; z=2: weights cvt + lT/lI zero.
    cvt_all<<<dim3(N_T / 64, DIM / 64, 3), 256, 0, stream>>>(
        image, text, w_text, w_image, image_bf, text_bf, imgT, textT,
        wt_bf, wi_bf, lT);

    gemm_proj3<<<dim3(N_T / 256, DIM / 128, 2), 512, AT_LDS_BYTES, stream>>>(
        text_bf, wt_bf, b_text, t_bf, image_bf, wi_bf, b_image, i_bf);

    gemm_logits_exp<<<dim3(N_T / 128, N_I / 128), 256, 0, stream>>>(t_bf, i_bf, P, PT, lT, lI);

    gemm_attn3<<<dim3(N_T / 256, DIM / 128, 2), 512, AT_LDS_BYTES, stream>>>(
        P, imgT, lT, scale_TI, out0, PT, textT, lI, scale_IT, out1);
}